// Round 2
// baseline (524.783 us; speedup 1.0000x reference)
//
#include <hip/hip_runtime.h>
#include <stdint.h>
#include <math.h>

#define LRES 8192
#define KNB  48
#define ASTR 296   // f16 row stride for A (148 words: only 2-way bank aliasing = free)

typedef _Float16 half_t;
typedef _Float16 half8 __attribute__((ext_vector_type(8)));
typedef float f4 __attribute__((ext_vector_type(4)));

// ---------------- prep: convert/reorder weights into workspace ----------------
// WeH [n=128][k'=288] f16 : k'<160 -> orig col k', k'>=160 -> orig col k'+128 (skip h_i block)
// WpH [n=128][k=128] f16  : Wproj as-is
// Wh32 [cc=128][n=128] f32: We[:,160+cc] transposed (feeds hbias_kernel)
// WposB [p=16][k=32] f16  : e_pos MFMA B; k 0..7 = geom w (Wpos col 32+k), 8..15 = 0, 16..31 = rbf w (Wpos col k)
__global__ void prep_kernel(const float* __restrict__ We, const float* __restrict__ Wproj,
                            const float* __restrict__ Wpos,
                            half_t* __restrict__ WeH, half_t* __restrict__ WpH,
                            float* __restrict__ Wh32, half_t* __restrict__ WposB) {
  int t = blockIdx.x * blockDim.x + threadIdx.x;
  if (t < 128 * 288) {
    int n = t / 288, kp = t % 288;
    int k = kp < 160 ? kp : kp + 128;
    WeH[n * 288 + kp] = (half_t)We[n * 416 + k];
  }
  if (t < 128 * 128) {
    int n = t >> 7, k = t & 127;
    WpH[t] = (half_t)Wproj[t];
    Wh32[k * 128 + n] = We[n * 416 + 160 + k];
  }
  if (t < 512) {
    int p = t >> 5, k = t & 31;
    float v = (k < 8) ? Wpos[p * 66 + 32 + k] : ((k < 16) ? 0.0f : Wpos[p * 66 + k]);
    WposB[t] = (half_t)v;
  }
}

// ---------------- hbias: hb[i][n] = sum_cc We[n][160+cc] * node_h[i][cc] ----------------
// Hoisted rank-128 h_i bias: was a serial 128-deep GEMV (64 KB L2 read) inside EVERY edge block.
__global__ __launch_bounds__(256) void hbias_kernel(const float* __restrict__ node_h,
                                                    const float* __restrict__ Wh32,
                                                    float* __restrict__ hb) {
  __shared__ float hrow[4][128];
  const int i0 = blockIdx.x * 4;
  const int t = threadIdx.x;
  for (int u = t; u < 512; u += 256) hrow[u >> 7][u & 127] = node_h[(size_t)i0 * 128 + u];
  __syncthreads();
  const int n = t & 127, g = t >> 7;
  float s0 = 0.f, s1 = 0.f;
#pragma unroll 8
  for (int cc = 0; cc < 128; ++cc) {
    float w = Wh32[cc * 128 + n];         // coalesced 512B per cc across 128 threads
    s0 = fmaf(w, hrow[g][cc], s0);        // LDS broadcast
    s1 = fmaf(w, hrow[g + 2][cc], s1);
  }
  hb[(size_t)(i0 + g) * 128 + n] = s0;
  hb[(size_t)(i0 + g + 2) * 128 + n] = s1;
}

// ---------------- knn: exact top-48 ordered by float64 (D, idx) ----------------
// Pass-1 result (10-bit histogram bin) is cached in packed registers; pass 2 no longer
// reloads X or recomputes distances except for the rare (<=256/8192) candidate fp64 path.
__global__ __launch_bounds__(256) void knn_kernel(const float* __restrict__ X,
                                                  int* __restrict__ out_idx,
                                                  float* __restrict__ out_D) {
  __shared__ unsigned hist[1024];
  __shared__ unsigned psum[256];
  __shared__ double candD[256];
  __shared__ int candJ[256];
  __shared__ unsigned cnt;
  __shared__ int bstar_s;
  const int i = blockIdx.x;
  const int tid = threadIdx.x;
  const float xi = X[i * 3 + 0], yi = X[i * 3 + 1], zi = X[i * 3 + 2];
  for (int b = tid; b < 1024; b += 256) hist[b] = 0u;
  if (tid == 0) cnt = 0u;
  __syncthreads();
  // pass 1: fp32 distances -> histogram; bin cached in registers (2 x 16-bit per word)
  unsigned binp[16];
#pragma unroll
  for (int it = 0; it < 32; ++it) {
    int j = tid + it * 256;
    float dx = X[j * 3 + 0] - xi;
    float dy = X[j * 3 + 1] - yi;
    float dz = X[j * 3 + 2] - zi;
    float D = sqrtf(dx * dx + dy * dy + dz * dz + 1e-6f);
    int b = (int)(D * 4.0f); if (b > 1023) b = 1023;
    if (it & 1) binp[it >> 1] |= (unsigned)b << 16; else binp[it >> 1] = (unsigned)b;
    atomicAdd(&hist[b], 1u);
  }
  __syncthreads();
  unsigned s4 = hist[tid * 4 + 0] + hist[tid * 4 + 1] + hist[tid * 4 + 2] + hist[tid * 4 + 3];
  psum[tid] = s4;
  __syncthreads();
  if (tid == 0) {
    unsigned run = 0; int g = 0;
    while (g < 255 && run + psum[g] < KNB) { run += psum[g]; ++g; }
    int b = g * 4;
    while (b < g * 4 + 3 && run + hist[b] < KNB) { run += hist[b]; ++b; }
    bstar_s = b;
  }
  __syncthreads();
  int bthr = bstar_s + 1; if (bthr > 1023) bthr = 1023;  // +1 bin slack covers fp32 vs fp64
  const double xid = (double)xi, yid = (double)yi, zid = (double)zi;
  // pass 2: register bin test; fp64 exact key only for candidates
#pragma unroll
  for (int it = 0; it < 32; ++it) {
    int b = (int)((binp[it >> 1] >> ((it & 1) * 16)) & 0xFFFFu);
    if (b <= bthr) {
      int j = tid + it * 256;
      unsigned p = atomicAdd(&cnt, 1u);
      if (p < 256u) {
        double ddx = (double)X[j * 3 + 0] - xid;
        double ddy = (double)X[j * 3 + 1] - yid;
        double ddz = (double)X[j * 3 + 2] - zid;
        candD[p] = sqrt(ddx * ddx + ddy * ddy + ddz * ddz + 1e-6);
        candJ[p] = j;
      }
    }
  }
  __syncthreads();
  unsigned n = cnt;
  if (tid >= (int)n) { candD[tid] = INFINITY; candJ[tid] = 0x7FFFFFFF; }
  __syncthreads();
  // bitonic sort 256 (D,idx) ascending lexicographic == jax top_k order
  for (unsigned size = 2; size <= 256; size <<= 1) {
    for (unsigned stride = size >> 1; stride > 0; stride >>= 1) {
      unsigned partner = (unsigned)tid ^ stride;
      if (partner > (unsigned)tid) {
        double da = candD[tid], db = candD[partner];
        int ja = candJ[tid], jb = candJ[partner];
        bool agtb = (da > db) || (da == db && ja > jb);
        bool asc = ((tid & size) == 0);
        if (agtb == asc) {
          candD[tid] = db; candJ[tid] = jb;
          candD[partner] = da; candJ[partner] = ja;
        }
      }
      __syncthreads();
    }
  }
  if (tid < KNB) {
    out_idx[(size_t)i * KNB + tid] = candJ[tid];
    out_D[(size_t)i * KNB + tid] = (float)candD[tid];
  }
}

// ---------------- edge kernel: features + f16-MFMA GEMMs + LN, one block per residue ----------------
__global__ __launch_bounds__(256, 4) void edge_kernel(
    const float* __restrict__ X, const float* __restrict__ node_h,
    const float* __restrict__ f_node, const float* __restrict__ Wpos,
    const float* __restrict__ bpos, const float* __restrict__ ln_scale,
    const float* __restrict__ ln_bias, const float* __restrict__ bproj,
    const int* __restrict__ aatype, const int* __restrict__ residue_index,
    const int* __restrict__ ws_idx, const float* __restrict__ ws_D,
    const half_t* __restrict__ WeH, const half_t* __restrict__ WpH,
    const half_t* __restrict__ WposB, const float* __restrict__ hbAll,
    float* __restrict__ out) {
  __shared__ __align__(16) half_t Ald[48 * ASTR];   // 28416 B: e_in^T rows=edges, f16
  __shared__ float poolW[1056];                     // WposL; aliased by redS/mean/rstd after P2
  __shared__ float hbias[128], lnsL[128], lnbL[128], bprojL[128];
  __shared__ float bposL[16], DkL[48];
  __shared__ int jL[48], pidxL[48], aaL[48];

  float* redS  = poolW;          // [48][8] (sum,sq per wave) - after last poolW read (P2)
  float* meanL = poolW + 384;
  float* rstdL = poolW + 432;

  const int i = blockIdx.x;
  const int tid = threadIdx.x;
  const int w = tid >> 6;            // wave 0..3
  const int lane = tid & 63;
  const int lm = lane & 15;
  const int quad = lane >> 4;
  const int quad8 = quad * 8;
  const int n0 = w * 32 + lm;        // this wave's base output column

  // ---- P0: small loads + per-edge scalars; geom straight into Ald cols 128..135 (f16) ----
  if (tid < 128) {
    lnsL[tid] = ln_scale[tid];
    lnbL[tid] = ln_bias[tid];
    bprojL[tid] = bproj[tid];
    hbias[tid] = hbAll[(size_t)i * 128 + tid];   // precomputed h_i bias row
  }
  for (int t = tid; t < 1056; t += 256) poolW[t] = Wpos[t];
  if (tid < 16) bposL[tid] = bpos[tid];
  const float xi = X[i * 3 + 0], yi = X[i * 3 + 1], zi = X[i * 3 + 2];
  if (tid < KNB) {
    int e = tid;
    int j = ws_idx[(size_t)i * KNB + e];
    float Dk = ws_D[(size_t)i * KNB + e];
    jL[e] = j; DkL[e] = Dk;
    float xj = X[j * 3 + 0], yj = X[j * 3 + 1], zj = X[j * 3 + 2];
    float inv = 1.0f / (Dk + 1e-6f);
    half_t* gr = Ald + e * ASTR + 128;           // cols 128..135: geom f16 (MFMA A window)
    gr[0] = (half_t)(Dk / 10.0f);
    gr[1] = (half_t)(1.0f / (1.0f + Dk));
    gr[2] = (half_t)expf(-Dk);
    gr[3] = (half_t)sinf(Dk);
    gr[4] = (half_t)cosf(Dk);
    gr[5] = (half_t)((xj - xi) * inv);
    gr[6] = (half_t)((yj - yi) * inv);
    gr[7] = (half_t)((zj - zi) * inv);
    // cols 136..143 MUST be zeroed: B rows 8..15 are zero, but 0*NaN-garbage = NaN in the
    // e_pos MFMA. 16B of zeros per edge (gr+8 is 16B-aligned: e*592+256+16).
    *(uint2*)(gr + 8)  = (uint2){0u, 0u};
    *(uint2*)(gr + 12) = (uint2){0u, 0u};
    int off = residue_index[j] - residue_index[i] + 8;
    off = off < 0 ? 0 : (off > 15 ? 15 : off);
    pidxL[e] = off;
    aaL[e] = aatype[j];
  }
  __syncthreads();

  // ---- P1: rbf (f16, cols 144..159) + float4 gathers f_node->0..127, node_h[j]->160..287 ----
  for (int t = tid; t < KNB * 16; t += 256) {
    int e = t >> 4, m = t & 15;
    float z = (DkL[e] - (2.0f + (float)m * (20.0f / 15.0f))) * 0.8f;
    Ald[e * ASTR + 144 + m] = (half_t)expf(-z * z);
  }
  {
    const int c4 = lane & 31;       // float4 column
    const int sel = lane >> 5;      // 0: f_node, 1: node_h
#pragma unroll
    for (int it = 0; it < 12; ++it) {
      int e = it * 4 + w;
      size_t j = (size_t)jL[e];
      const float* src = (sel ? node_h : f_node) + j * 128 + 4 * c4;
      f4 v = *(const f4*)src;
      union { uint2 u; half_t h[4]; } p;
      p.h[0] = (half_t)v[0]; p.h[1] = (half_t)v[1];
      p.h[2] = (half_t)v[2]; p.h[3] = (half_t)v[3];
      *(uint2*)(Ald + e * ASTR + sel * 160 + 4 * c4) = p.u;
    }
  }
  // prefetch GEMM1 B into registers (72 VGPRs); latency hidden under gathers/P2
  half8 bregA[9], bregB[9];
#pragma unroll
  for (int ks = 0; ks < 9; ++ks) {
    bregA[ks] = *(const half8*)(WeH + (size_t)n0 * 288 + ks * 32 + quad8);
    bregB[ks] = *(const half8*)(WeH + (size_t)(n0 + 16) * 288 + ks * 32 + quad8);
  }
  __syncthreads();

  // ---- P2: e_pos via single MFMA per wave (K=32 window cols 128..159) + gather-adds ----
  if (w < 3) {
    half8 a = *(const half8*)(Ald + (w * 16 + lm) * ASTR + 128 + quad8);
    half8 bp = *(const half8*)(WposB + lm * 32 + quad8);
    f4 z = {};
    f4 ep = __builtin_amdgcn_mfma_f32_16x16x32_f16(a, bp, z, 0, 0, 0);
    const float* wp = poolW + lm * 66;
    float bb = bposL[lm];
#pragma unroll
    for (int r = 0; r < 4; ++r) {
      int m = w * 16 + quad * 4 + r;
      float s = ep[r] + bb + wp[pidxL[m]] + wp[40 + aaL[m]];
      Ald[m * ASTR + 128 + lm] = (half_t)s;      // overwrite geom/pad with e_pos
    }
  }
  __syncthreads();

  // ---- GEMM1: e = A(48x288) @ WeH^T via f16 MFMA; B already in registers ----
  f4 acc[3][2] = {};
#pragma unroll
  for (int ks = 0; ks < 9; ++ks) {
#pragma unroll
    for (int mt = 0; mt < 3; ++mt) {
      half8 a = *(const half8*)(Ald + (mt * 16 + lm) * ASTR + ks * 32 + quad8);
      acc[mt][0] = __builtin_amdgcn_mfma_f32_16x16x32_f16(a, bregA[ks], acc[mt][0], 0, 0, 0);
      acc[mt][1] = __builtin_amdgcn_mfma_f32_16x16x32_f16(a, bregB[ks], acc[mt][1], 0, 0, 0);
    }
  }
  // prefetch GEMM2 B (32 VGPRs); latency hidden under LN reduce
  half8 b2A[4], b2B[4];
#pragma unroll
  for (int ks = 0; ks < 4; ++ks) {
    b2A[ks] = *(const half8*)(WpH + (size_t)n0 * 128 + ks * 32 + quad8);
    b2B[ks] = *(const half8*)(WpH + (size_t)(n0 + 16) * 128 + ks * 32 + quad8);
  }

  // ---- add h_i bias; LN partials (sum over this wave's 32 cols via shfl) ----
  {
    float hb0 = hbias[n0], hb1 = hbias[n0 + 16];
#pragma unroll
    for (int mt = 0; mt < 3; ++mt)
#pragma unroll
      for (int r = 0; r < 4; ++r) { acc[mt][0][r] += hb0; acc[mt][1][r] += hb1; }
  }
#pragma unroll
  for (int mt = 0; mt < 3; ++mt)
#pragma unroll
    for (int r = 0; r < 4; ++r) {
      float e0 = acc[mt][0][r], e1 = acc[mt][1][r];
      float sv = e0 + e1;
      float qv = e0 * e0 + e1 * e1;
#pragma unroll
      for (int m = 1; m < 16; m <<= 1) {
        sv += __shfl_xor(sv, m, 16);
        qv += __shfl_xor(qv, m, 16);
      }
      if (lm == 0) {
        int row = mt * 16 + quad * 4 + r;
        redS[row * 8 + w * 2 + 0] = sv;
        redS[row * 8 + w * 2 + 1] = qv;
      }
    }
  __syncthreads();
  if (tid < KNB) {
    float s = redS[tid * 8 + 0] + redS[tid * 8 + 2] + redS[tid * 8 + 4] + redS[tid * 8 + 6];
    float q = redS[tid * 8 + 1] + redS[tid * 8 + 3] + redS[tid * 8 + 5] + redS[tid * 8 + 7];
    float m = s * (1.0f / 128.0f);
    float var = q * (1.0f / 128.0f) - m * m;
    meanL[tid] = m;
    rstdL[tid] = rsqrtf(var + 1e-5f);
  }
  __syncthreads();

  // ---- eln -> f16 back into Ald rows (cols 0..127), then GEMM2 ----
#pragma unroll
  for (int mt = 0; mt < 3; ++mt)
#pragma unroll
    for (int nt = 0; nt < 2; ++nt) {
      int n = n0 + nt * 16;
      float ls = lnsL[n], lb = lnbL[n];
#pragma unroll
      for (int r = 0; r < 4; ++r) {
        int m = mt * 16 + quad * 4 + r;
        float e = (acc[mt][nt][r] - meanL[m]) * rstdL[m] * ls + lb;
        Ald[m * ASTR + n] = (half_t)e;
      }
    }
  __syncthreads();

  f4 acc2[3][2] = {};
#pragma unroll
  for (int ks = 0; ks < 4; ++ks) {
#pragma unroll
    for (int mt = 0; mt < 3; ++mt) {
      half8 a = *(const half8*)(Ald + (mt * 16 + lm) * ASTR + ks * 32 + quad8);
      acc2[mt][0] = __builtin_amdgcn_mfma_f32_16x16x32_f16(a, b2A[ks], acc2[mt][0], 0, 0, 0);
      acc2[mt][1] = __builtin_amdgcn_mfma_f32_16x16x32_f16(a, b2B[ks], acc2[mt][1], 0, 0, 0);
    }
  }

  // ---- epilogue ----
#pragma unroll
  for (int mt = 0; mt < 3; ++mt)
#pragma unroll
    for (int nt = 0; nt < 2; ++nt) {
      int n = n0 + nt * 16;
      float bp = bprojL[n];
#pragma unroll
      for (int r = 0; r < 4; ++r) {
        int m = mt * 16 + quad * 4 + r;
        out[((size_t)i * KNB + m) * 128 + n] = acc2[mt][nt][r] + bp;
      }
    }
}

extern "C" void kernel_launch(void* const* d_in, const int* in_sizes, int n_in,
                              void* d_out, int out_size, void* d_ws, size_t ws_size,
                              hipStream_t stream) {
  const float* X        = (const float*)d_in[0];
  const float* node_h   = (const float*)d_in[1];
  const float* f_node   = (const float*)d_in[2];
  const float* Wpos     = (const float*)d_in[3];
  const float* bpos     = (const float*)d_in[4];
  const float* We       = (const float*)d_in[5];
  const float* ln_scale = (const float*)d_in[6];
  const float* ln_bias  = (const float*)d_in[7];
  const float* Wproj    = (const float*)d_in[8];
  const float* bproj    = (const float*)d_in[9];
  const int*   aatype   = (const int*)d_in[10];
  const int*   residue_index = (const int*)d_in[11];
  float* out = (float*)d_out;

  char* ws = (char*)d_ws;
  int*    ws_idx = (int*)ws;                     // 1.5 MB
  float*  ws_D   = (float*)(ws + 1572864);       // 1.5 MB
  half_t* WeH    = (half_t*)(ws + 3145728);      // 73728 B
  half_t* WpH    = (half_t*)(ws + 3219456);      // 32768 B
  float*  Wh32   = (float*)(ws + 3252224);       // 65536 B
  half_t* WposB  = (half_t*)(ws + 3317760);      // 1024 B
  float*  hbAll  = (float*)(ws + 3318784);       // 4 MB -> total 7513088 B

  prep_kernel<<<144, 256, 0, stream>>>(We, Wproj, Wpos, WeH, WpH, Wh32, WposB);
  hbias_kernel<<<2048, 256, 0, stream>>>(node_h, Wh32, hbAll);
  knn_kernel<<<LRES, 256, 0, stream>>>(X, ws_idx, ws_D);
  edge_kernel<<<LRES, 256, 0, stream>>>(X, node_h, f_node, Wpos, bpos, ln_scale,
                                        ln_bias, bproj, aatype, residue_index,
                                        ws_idx, ws_D, WeH, WpH, WposB, hbAll, out);
}

// Round 3
// 393.961 us; speedup vs baseline: 1.3321x; 1.3321x over previous
//
#include <hip/hip_runtime.h>
#include <stdint.h>
#include <math.h>

#define LRES 8192
#define KNB  48
#define ASTR 296   // f16 row stride for A (148 words: only 2-way bank aliasing = free)

typedef _Float16 half_t;
typedef _Float16 half8 __attribute__((ext_vector_type(8)));
typedef float f4 __attribute__((ext_vector_type(4)));

// ---------------- prep: convert/reorder weights into workspace ----------------
// WeH [n=128][k'=288] f16 : k'<160 -> orig col k', k'>=160 -> orig col k'+128 (skip h_i block)
// WpH [n=128][k=128] f16  : Wproj as-is
// Wh32 [cc=128][n=128] f32: We[:,160+cc] transposed (feeds hbias_kernel)
// WposB [p=16][k=32] f16  : e_pos MFMA B; k 0..7 = geom w (Wpos col 32+k), 8..15 = 0, 16..31 = rbf w (Wpos col k)
__global__ void prep_kernel(const float* __restrict__ We, const float* __restrict__ Wproj,
                            const float* __restrict__ Wpos,
                            half_t* __restrict__ WeH, half_t* __restrict__ WpH,
                            float* __restrict__ Wh32, half_t* __restrict__ WposB) {
  int t = blockIdx.x * blockDim.x + threadIdx.x;
  if (t < 128 * 288) {
    int n = t / 288, kp = t % 288;
    int k = kp < 160 ? kp : kp + 128;
    WeH[n * 288 + kp] = (half_t)We[n * 416 + k];
  }
  if (t < 128 * 128) {
    int n = t >> 7, k = t & 127;
    WpH[t] = (half_t)Wproj[t];
    Wh32[k * 128 + n] = We[n * 416 + 160 + k];
  }
  if (t < 512) {
    int p = t >> 5, k = t & 31;
    float v = (k < 8) ? Wpos[p * 66 + 32 + k] : ((k < 16) ? 0.0f : Wpos[p * 66 + k]);
    WposB[t] = (half_t)v;
  }
}

// ---------------- hbias: hb[i][n] = sum_cc We[n][160+cc] * node_h[i][cc] ----------------
__global__ __launch_bounds__(256) void hbias_kernel(const float* __restrict__ node_h,
                                                    const float* __restrict__ Wh32,
                                                    float* __restrict__ hb) {
  __shared__ float hrow[4][128];
  const int i0 = blockIdx.x * 4;
  const int t = threadIdx.x;
  for (int u = t; u < 512; u += 256) hrow[u >> 7][u & 127] = node_h[(size_t)i0 * 128 + u];
  __syncthreads();
  const int n = t & 127, g = t >> 7;
  float s0 = 0.f, s1 = 0.f;
#pragma unroll 8
  for (int cc = 0; cc < 128; ++cc) {
    float w = Wh32[cc * 128 + n];         // coalesced 512B per cc across 128 threads
    s0 = fmaf(w, hrow[g][cc], s0);        // LDS broadcast
    s1 = fmaf(w, hrow[g + 2][cc], s1);
  }
  hb[(size_t)(i0 + g) * 128 + n] = s0;
  hb[(size_t)(i0 + g + 2) * 128 + n] = s1;
}

// ---------------- knn: exact top-48 ordered by float64 (D, idx) ----------------
// pass 1: float4-vectorized (4 pts / 3 loads), fp32 bins cached in packed registers.
// selection: exact candidate count from histogram prefix; common case (count<=64) sorts
// in wave-0 REGISTERS via shuffle bitonic (21 stages, 0 barriers, 0 LDS) -- identical
// (D64, idx) lexicographic order as the 256-way LDS bitonic fallback.
__global__ __launch_bounds__(256) void knn_kernel(const float* __restrict__ X,
                                                  int* __restrict__ out_idx,
                                                  float* __restrict__ out_D) {
  __shared__ unsigned hist[1024];
  __shared__ unsigned psum[256];
  __shared__ double candD[256];
  __shared__ int candJ[256];
  __shared__ unsigned cnt;
  __shared__ int bstar_s;
  __shared__ unsigned cexp_s;
  const int i = blockIdx.x;
  const int tid = threadIdx.x;
  const float xi = X[i * 3 + 0], yi = X[i * 3 + 1], zi = X[i * 3 + 2];
  for (int b = tid; b < 1024; b += 256) hist[b] = 0u;
  if (tid == 0) cnt = 0u;
  __syncthreads();
  // pass 1: 4 points per 3 aligned float4 loads; bin -> histogram + packed registers
  unsigned binp[16];
#pragma unroll
  for (int it = 0; it < 8; ++it) {
    int jb = (tid + it * 256) * 4;               // base point; jb*3 floats = 48B, 16B-aligned
    const float* xp = X + (size_t)jb * 3;
    f4 r0 = *(const f4*)(xp);
    f4 r1 = *(const f4*)(xp + 4);
    f4 r2 = *(const f4*)(xp + 8);
    float px[4] = {r0[0], r0[3], r1[2], r2[1]};
    float py[4] = {r0[1], r1[0], r1[3], r2[2]};
    float pz[4] = {r0[2], r1[1], r2[0], r2[3]};
#pragma unroll
    for (int q = 0; q < 4; ++q) {
      float dx = px[q] - xi, dy = py[q] - yi, dz = pz[q] - zi;
      float D = sqrtf(dx * dx + dy * dy + dz * dz + 1e-6f);
      int b = (int)(D * 4.0f); if (b > 1023) b = 1023;
      int idx = it * 4 + q;
      if (idx & 1) binp[idx >> 1] |= (unsigned)b << 16; else binp[idx >> 1] = (unsigned)b;
      atomicAdd(&hist[b], 1u);
    }
  }
  __syncthreads();
  unsigned s4 = hist[tid * 4 + 0] + hist[tid * 4 + 1] + hist[tid * 4 + 2] + hist[tid * 4 + 3];
  psum[tid] = s4;
  __syncthreads();
  if (tid == 0) {
    unsigned run = 0; int g = 0;
    while (g < 255 && run + psum[g] < KNB) { run += psum[g]; ++g; }
    int b = g * 4;
    while (b < g * 4 + 3 && run + hist[b] < KNB) { run += hist[b]; ++b; }
    bstar_s = b;
    // exact candidate count through bin bthr = min(b+1, 1023)
    unsigned tot = run + hist[b];
    if (b < 1023) tot += hist[b + 1];
    cexp_s = tot;
  }
  __syncthreads();
  int bthr = bstar_s + 1; if (bthr > 1023) bthr = 1023;  // +1 bin slack covers fp32 vs fp64
  const unsigned cexp = cexp_s;
  const double xid = (double)xi, yid = (double)yi, zid = (double)zi;
  // pass 2: branchless candidate mask from cached bins, then rolled fp64-key collection
  {
    unsigned cmask = 0u;
#pragma unroll
    for (int idx = 0; idx < 32; ++idx) {
      int b = (int)((binp[idx >> 1] >> ((idx & 1) * 16)) & 0xFFFFu);
      if (b <= bthr) cmask |= (1u << idx);
    }
    while (cmask) {
      int k = __builtin_ctz(cmask);
      cmask &= cmask - 1u;
      int j = (tid + (k >> 2) * 256) * 4 + (k & 3);
      unsigned p = atomicAdd(&cnt, 1u);
      if (p < 256u) {
        double ddx = (double)X[j * 3 + 0] - xid;
        double ddy = (double)X[j * 3 + 1] - yid;
        double ddz = (double)X[j * 3 + 2] - zid;
        candD[p] = sqrt(ddx * ddx + ddy * ddy + ddz * ddz + 1e-6);
        candJ[p] = j;
      }
    }
  }
  __syncthreads();
  unsigned n = cnt;
  if (cexp <= 64u) {
    // ---- common path: wave-0 register bitonic over 64 (double,int) keys ----
    if (tid < 64) {
      double d = (tid < (int)n) ? candD[tid] : INFINITY;
      int j = (tid < (int)n) ? candJ[tid] : 0x7FFFFFFF;
#pragma unroll
      for (int size = 2; size <= 64; size <<= 1) {
#pragma unroll
        for (int stride = 32; stride > 0; stride >>= 1) {
          if (stride >= size) continue;            // compile-time pruned
          double dp = __shfl_xor(d, stride, 64);
          int jp = __shfl_xor(j, stride, 64);
          bool up = ((tid & size) == 0);
          bool lower = ((tid & stride) == 0);
          bool mine_gt = (d > dp) || (d == dp && j > jp);
          bool part_gt = (dp > d) || (dp == d && jp > j);
          bool keep = lower ? (mine_gt != up) : (part_gt != up);
          d = keep ? d : dp;
          j = keep ? j : jp;
        }
      }
      if (tid < KNB) {
        out_idx[(size_t)i * KNB + tid] = j;
        out_D[(size_t)i * KNB + tid] = (float)d;
      }
    }
    return;
  }
  // ---- fallback (count in (64,256]): original 256-way LDS bitonic ----
  if (tid >= (int)n) { candD[tid] = INFINITY; candJ[tid] = 0x7FFFFFFF; }
  __syncthreads();
  for (unsigned size = 2; size <= 256; size <<= 1) {
    for (unsigned stride = size >> 1; stride > 0; stride >>= 1) {
      unsigned partner = (unsigned)tid ^ stride;
      if (partner > (unsigned)tid) {
        double da = candD[tid], db = candD[partner];
        int ja = candJ[tid], jb = candJ[partner];
        bool agtb = (da > db) || (da == db && ja > jb);
        bool asc = ((tid & size) == 0);
        if (agtb == asc) {
          candD[tid] = db; candJ[tid] = jb;
          candD[partner] = da; candJ[partner] = ja;
        }
      }
      __syncthreads();
    }
  }
  if (tid < KNB) {
    out_idx[(size_t)i * KNB + tid] = candJ[tid];
    out_D[(size_t)i * KNB + tid] = (float)candD[tid];
  }
}

// ---------------- edge kernel: features + f16-MFMA GEMMs + LN, one block per residue ----------------
__global__ __launch_bounds__(256, 4) void edge_kernel(
    const float* __restrict__ X, const float* __restrict__ node_h,
    const float* __restrict__ f_node, const float* __restrict__ Wpos,
    const float* __restrict__ bpos, const float* __restrict__ ln_scale,
    const float* __restrict__ ln_bias, const float* __restrict__ bproj,
    const int* __restrict__ aatype, const int* __restrict__ residue_index,
    const int* __restrict__ ws_idx, const float* __restrict__ ws_D,
    const half_t* __restrict__ WeH, const half_t* __restrict__ WpH,
    const half_t* __restrict__ WposB, const float* __restrict__ hbAll,
    float* __restrict__ out) {
  __shared__ __align__(16) half_t Ald[48 * ASTR];   // 28416 B: e_in^T rows=edges, f16
  __shared__ float poolW[1056];                     // WposL; aliased by redS/mean/rstd after P2
  __shared__ float hbias[128], lnsL[128], lnbL[128], bprojL[128];
  __shared__ float bposL[16], DkL[48];
  __shared__ int jL[48], pidxL[48], aaL[48];

  float* redS  = poolW;          // [48][8] (sum,sq per wave) - after last poolW read (P2)
  float* meanL = poolW + 384;
  float* rstdL = poolW + 432;

  const int i = blockIdx.x;
  const int tid = threadIdx.x;
  const int w = tid >> 6;            // wave 0..3
  const int lane = tid & 63;
  const int lm = lane & 15;
  const int quad = lane >> 4;
  const int quad8 = quad * 8;
  const int n0 = w * 32 + lm;        // this wave's base output column

  // ---- P0: small loads + per-edge scalars; geom straight into Ald cols 128..135 (f16) ----
  if (tid < 128) {
    lnsL[tid] = ln_scale[tid];
    lnbL[tid] = ln_bias[tid];
    bprojL[tid] = bproj[tid];
    hbias[tid] = hbAll[(size_t)i * 128 + tid];   // precomputed h_i bias row
  }
  for (int t = tid; t < 1056; t += 256) poolW[t] = Wpos[t];
  if (tid < 16) bposL[tid] = bpos[tid];
  const float xi = X[i * 3 + 0], yi = X[i * 3 + 1], zi = X[i * 3 + 2];
  if (tid < KNB) {
    int e = tid;
    int j = ws_idx[(size_t)i * KNB + e];
    float Dk = ws_D[(size_t)i * KNB + e];
    jL[e] = j; DkL[e] = Dk;
    float xj = X[j * 3 + 0], yj = X[j * 3 + 1], zj = X[j * 3 + 2];
    float inv = 1.0f / (Dk + 1e-6f);
    half_t* gr = Ald + e * ASTR + 128;           // cols 128..135: geom f16 (MFMA A window)
    gr[0] = (half_t)(Dk / 10.0f);
    gr[1] = (half_t)(1.0f / (1.0f + Dk));
    gr[2] = (half_t)expf(-Dk);
    gr[3] = (half_t)sinf(Dk);
    gr[4] = (half_t)cosf(Dk);
    gr[5] = (half_t)((xj - xi) * inv);
    gr[6] = (half_t)((yj - yi) * inv);
    gr[7] = (half_t)((zj - zi) * inv);
    // cols 136..143 MUST be zeroed: B rows 8..15 are zero, but 0*NaN-garbage = NaN in the
    // e_pos MFMA. 16B of zeros per edge (gr+8 is 16B-aligned: e*592+256+16).
    *(uint2*)(gr + 8)  = (uint2){0u, 0u};
    *(uint2*)(gr + 12) = (uint2){0u, 0u};
    int off = residue_index[j] - residue_index[i] + 8;
    off = off < 0 ? 0 : (off > 15 ? 15 : off);
    pidxL[e] = off;
    aaL[e] = aatype[j];
  }
  __syncthreads();

  // ---- P1: rbf (f16, cols 144..159) + float4 gathers f_node->0..127, node_h[j]->160..287 ----
  for (int t = tid; t < KNB * 16; t += 256) {
    int e = t >> 4, m = t & 15;
    float z = (DkL[e] - (2.0f + (float)m * (20.0f / 15.0f))) * 0.8f;
    Ald[e * ASTR + 144 + m] = (half_t)expf(-z * z);
  }
  {
    const int c4 = lane & 31;       // float4 column
    const int sel = lane >> 5;      // 0: f_node, 1: node_h
#pragma unroll
    for (int it = 0; it < 12; ++it) {
      int e = it * 4 + w;
      size_t j = (size_t)jL[e];
      const float* src = (sel ? node_h : f_node) + j * 128 + 4 * c4;
      f4 v = *(const f4*)src;
      union { uint2 u; half_t h[4]; } p;
      p.h[0] = (half_t)v[0]; p.h[1] = (half_t)v[1];
      p.h[2] = (half_t)v[2]; p.h[3] = (half_t)v[3];
      *(uint2*)(Ald + e * ASTR + sel * 160 + 4 * c4) = p.u;
    }
  }
  // prefetch GEMM1 B into registers (72 VGPRs); latency hidden under gathers/P2
  half8 bregA[9], bregB[9];
#pragma unroll
  for (int ks = 0; ks < 9; ++ks) {
    bregA[ks] = *(const half8*)(WeH + (size_t)n0 * 288 + ks * 32 + quad8);
    bregB[ks] = *(const half8*)(WeH + (size_t)(n0 + 16) * 288 + ks * 32 + quad8);
  }
  __syncthreads();

  // ---- P2: e_pos via single MFMA per wave (K=32 window cols 128..159) + gather-adds ----
  if (w < 3) {
    half8 a = *(const half8*)(Ald + (w * 16 + lm) * ASTR + 128 + quad8);
    half8 bp = *(const half8*)(WposB + lm * 32 + quad8);
    f4 z = {};
    f4 ep = __builtin_amdgcn_mfma_f32_16x16x32_f16(a, bp, z, 0, 0, 0);
    const float* wp = poolW + lm * 66;
    float bb = bposL[lm];
#pragma unroll
    for (int r = 0; r < 4; ++r) {
      int m = w * 16 + quad * 4 + r;
      float s = ep[r] + bb + wp[pidxL[m]] + wp[40 + aaL[m]];
      Ald[m * ASTR + 128 + lm] = (half_t)s;      // overwrite geom/pad with e_pos
    }
  }
  __syncthreads();

  // ---- GEMM1: e = A(48x288) @ WeH^T via f16 MFMA; B already in registers ----
  f4 acc[3][2] = {};
#pragma unroll
  for (int ks = 0; ks < 9; ++ks) {
#pragma unroll
    for (int mt = 0; mt < 3; ++mt) {
      half8 a = *(const half8*)(Ald + (mt * 16 + lm) * ASTR + ks * 32 + quad8);
      acc[mt][0] = __builtin_amdgcn_mfma_f32_16x16x32_f16(a, bregA[ks], acc[mt][0], 0, 0, 0);
      acc[mt][1] = __builtin_amdgcn_mfma_f32_16x16x32_f16(a, bregB[ks], acc[mt][1], 0, 0, 0);
    }
  }
  // prefetch GEMM2 B (32 VGPRs); latency hidden under LN reduce
  half8 b2A[4], b2B[4];
#pragma unroll
  for (int ks = 0; ks < 4; ++ks) {
    b2A[ks] = *(const half8*)(WpH + (size_t)n0 * 128 + ks * 32 + quad8);
    b2B[ks] = *(const half8*)(WpH + (size_t)(n0 + 16) * 128 + ks * 32 + quad8);
  }

  // ---- add h_i bias; LN partials (sum over this wave's 32 cols via shfl) ----
  {
    float hb0 = hbias[n0], hb1 = hbias[n0 + 16];
#pragma unroll
    for (int mt = 0; mt < 3; ++mt)
#pragma unroll
      for (int r = 0; r < 4; ++r) { acc[mt][0][r] += hb0; acc[mt][1][r] += hb1; }
  }
#pragma unroll
  for (int mt = 0; mt < 3; ++mt)
#pragma unroll
    for (int r = 0; r < 4; ++r) {
      float e0 = acc[mt][0][r], e1 = acc[mt][1][r];
      float sv = e0 + e1;
      float qv = e0 * e0 + e1 * e1;
#pragma unroll
      for (int m = 1; m < 16; m <<= 1) {
        sv += __shfl_xor(sv, m, 16);
        qv += __shfl_xor(qv, m, 16);
      }
      if (lm == 0) {
        int row = mt * 16 + quad * 4 + r;
        redS[row * 8 + w * 2 + 0] = sv;
        redS[row * 8 + w * 2 + 1] = qv;
      }
    }
  __syncthreads();
  if (tid < KNB) {
    float s = redS[tid * 8 + 0] + redS[tid * 8 + 2] + redS[tid * 8 + 4] + redS[tid * 8 + 6];
    float q = redS[tid * 8 + 1] + redS[tid * 8 + 3] + redS[tid * 8 + 5] + redS[tid * 8 + 7];
    float m = s * (1.0f / 128.0f);
    float var = q * (1.0f / 128.0f) - m * m;
    meanL[tid] = m;
    rstdL[tid] = rsqrtf(var + 1e-5f);
  }
  __syncthreads();

  // ---- eln -> f16 back into Ald rows (cols 0..127), then GEMM2 ----
#pragma unroll
  for (int mt = 0; mt < 3; ++mt)
#pragma unroll
    for (int nt = 0; nt < 2; ++nt) {
      int n = n0 + nt * 16;
      float ls = lnsL[n], lb = lnbL[n];
#pragma unroll
      for (int r = 0; r < 4; ++r) {
        int m = mt * 16 + quad * 4 + r;
        float e = (acc[mt][nt][r] - meanL[m]) * rstdL[m] * ls + lb;
        Ald[m * ASTR + n] = (half_t)e;
      }
    }
  __syncthreads();

  f4 acc2[3][2] = {};
#pragma unroll
  for (int ks = 0; ks < 4; ++ks) {
#pragma unroll
    for (int mt = 0; mt < 3; ++mt) {
      half8 a = *(const half8*)(Ald + (mt * 16 + lm) * ASTR + ks * 32 + quad8);
      acc2[mt][0] = __builtin_amdgcn_mfma_f32_16x16x32_f16(a, b2A[ks], acc2[mt][0], 0, 0, 0);
      acc2[mt][1] = __builtin_amdgcn_mfma_f32_16x16x32_f16(a, b2B[ks], acc2[mt][1], 0, 0, 0);
    }
  }

  // ---- epilogue ----
#pragma unroll
  for (int mt = 0; mt < 3; ++mt)
#pragma unroll
    for (int nt = 0; nt < 2; ++nt) {
      int n = n0 + nt * 16;
      float bp = bprojL[n];
#pragma unroll
      for (int r = 0; r < 4; ++r) {
        int m = mt * 16 + quad * 4 + r;
        out[((size_t)i * KNB + m) * 128 + n] = acc2[mt][nt][r] + bp;
      }
    }
}

extern "C" void kernel_launch(void* const* d_in, const int* in_sizes, int n_in,
                              void* d_out, int out_size, void* d_ws, size_t ws_size,
                              hipStream_t stream) {
  const float* X        = (const float*)d_in[0];
  const float* node_h   = (const float*)d_in[1];
  const float* f_node   = (const float*)d_in[2];
  const float* Wpos     = (const float*)d_in[3];
  const float* bpos     = (const float*)d_in[4];
  const float* We       = (const float*)d_in[5];
  const float* ln_scale = (const float*)d_in[6];
  const float* ln_bias  = (const float*)d_in[7];
  const float* Wproj    = (const float*)d_in[8];
  const float* bproj    = (const float*)d_in[9];
  const int*   aatype   = (const int*)d_in[10];
  const int*   residue_index = (const int*)d_in[11];
  float* out = (float*)d_out;

  char* ws = (char*)d_ws;
  int*    ws_idx = (int*)ws;                     // 1.5 MB
  float*  ws_D   = (float*)(ws + 1572864);       // 1.5 MB
  half_t* WeH    = (half_t*)(ws + 3145728);      // 73728 B
  half_t* WpH    = (half_t*)(ws + 3219456);      // 32768 B
  float*  Wh32   = (float*)(ws + 3252224);       // 65536 B
  half_t* WposB  = (half_t*)(ws + 3317760);      // 1024 B
  float*  hbAll  = (float*)(ws + 3318784);       // 4 MB -> total 7513088 B

  prep_kernel<<<144, 256, 0, stream>>>(We, Wproj, Wpos, WeH, WpH, Wh32, WposB);
  hbias_kernel<<<2048, 256, 0, stream>>>(node_h, Wh32, hbAll);
  knn_kernel<<<LRES, 256, 0, stream>>>(X, ws_idx, ws_D);
  edge_kernel<<<LRES, 256, 0, stream>>>(X, node_h, f_node, Wpos, bpos, ln_scale,
                                        ln_bias, bproj, aatype, residue_index,
                                        ws_idx, ws_D, WeH, WpH, WposB, hbAll, out);
}